// Round 1
// baseline (1131.922 us; speedup 1.0000x reference)
//
#include <hip/hip_runtime.h>

#define N_NODES 100000
#define N_EDGES 1600000
#define BN_EPS 1e-5f

// ---------------------------------------------------------------------------
// scatter: 4 edges per 256-thread block; lane = feature. Gather feat[src] row
// (coalesced 256B) and atomic-add into agg[dst] row. Optionally count edges.
// ---------------------------------------------------------------------------
__global__ __launch_bounds__(256) void scatter_kernel(
    const float* __restrict__ feat, const int* __restrict__ src,
    const int* __restrict__ dst, float* __restrict__ agg,
    float* __restrict__ cnt)
{
    int e = blockIdx.x * 4 + (threadIdx.x >> 6);
    int lane = threadIdx.x & 63;
    if (e >= N_EDGES) return;
    int s = src[e];
    int d = dst[e];
    atomicAdd(&agg[d * 64 + lane], feat[s * 64 + lane]);
    if (cnt != nullptr && lane == 0) atomicAdd(&cnt[d], 1.0f);
}

// ---------------------------------------------------------------------------
// dense1: h = (agg/cnt) @ W1l^T + x @ W1r^T + b1, plus per-feature partial
// sums (Sum h, Sum h^2) for BatchNorm, reduced per block then one atomic per
// feature per block. 64 nodes per 256-thread block; each wave = one node slot
// (wave-uniform row pointers -> scalar/broadcast loads). Weights transposed
// into LDS: wl[k*64+f] -> lanes f consecutive -> 2-way bank alias (free).
// ---------------------------------------------------------------------------
__global__ __launch_bounds__(256) void dense1_kernel(
    const float* __restrict__ agg, const float* __restrict__ cnt,
    const float* __restrict__ x, const float* __restrict__ W1l,
    const float* __restrict__ W1r, const float* __restrict__ b1,
    float* __restrict__ h, float* __restrict__ sums, float* __restrict__ sumsq)
{
    __shared__ float wl[64 * 64];
    __shared__ float wr[64 * 64];
    for (int idx = threadIdx.x; idx < 64 * 64; idx += 256) {
        int f = idx >> 6, k = idx & 63;        // W[f][k] row-major
        wl[k * 64 + f] = W1l[idx];             // transposed
        wr[k * 64 + f] = W1r[idx];
    }
    __syncthreads();

    int f  = threadIdx.x & 63;
    int nl = threadIdx.x >> 6;                 // wave id = node slot
    float bias = b1[f];
    float s1 = 0.f, s2 = 0.f;
    int node0 = blockIdx.x * 64;

    for (int nn = 0; nn < 16; ++nn) {
        int node = node0 + nn * 4 + nl;
        if (node < N_NODES) {
            const float* ar = agg + (size_t)node * 64;
            const float* xr = x   + (size_t)node * 64;
            float ic = 1.0f / fmaxf(cnt[node], 1.0f);
            float acca = 0.f, accx = 0.f;
#pragma unroll
            for (int k = 0; k < 64; ++k) {
                acca += ar[k] * wl[k * 64 + f];
                accx += xr[k] * wr[k * 64 + f];
            }
            float acc = bias + acca * ic + accx;
            h[(size_t)node * 64 + f] = acc;
            s1 += acc;
            s2 += acc * acc;
        }
    }

    __shared__ float red[256];
    red[threadIdx.x] = s1;
    __syncthreads();
    if (threadIdx.x < 64) {
        float t = red[threadIdx.x] + red[threadIdx.x + 64] +
                  red[threadIdx.x + 128] + red[threadIdx.x + 192];
        atomicAdd(&sums[threadIdx.x], t);
    }
    __syncthreads();
    red[threadIdx.x] = s2;
    __syncthreads();
    if (threadIdx.x < 64) {
        float t = red[threadIdx.x] + red[threadIdx.x + 64] +
                  red[threadIdx.x + 128] + red[threadIdx.x + 192];
        atomicAdd(&sumsq[threadIdx.x], t);
    }
}

// ---------------------------------------------------------------------------
// BN finalize: mu/var (biased) -> affine scale/shift. One tiny block.
// ---------------------------------------------------------------------------
__global__ void bn_finalize_kernel(
    const float* __restrict__ sums, const float* __restrict__ sumsq,
    const float* __restrict__ gamma, const float* __restrict__ beta,
    float* __restrict__ scale, float* __restrict__ shift)
{
    int f = threadIdx.x;
    if (f < 64) {
        float inv_n = 1.0f / (float)N_NODES;
        float mu  = sums[f] * inv_n;
        float var = sumsq[f] * inv_n - mu * mu;
        float rs  = rsqrtf(var + BN_EPS);
        float sc  = gamma[f] * rs;
        scale[f] = sc;
        shift[f] = beta[f] - mu * sc;
    }
}

// ---------------------------------------------------------------------------
// BN apply + ReLU, in place, float4 vectorized.
// ---------------------------------------------------------------------------
__global__ __launch_bounds__(256) void bn_apply_kernel(
    float* __restrict__ h, const float* __restrict__ scale,
    const float* __restrict__ shift)
{
    __shared__ float sc[64], sh[64];
    if (threadIdx.x < 64) {
        sc[threadIdx.x] = scale[threadIdx.x];
        sh[threadIdx.x] = shift[threadIdx.x];
    }
    __syncthreads();
    int i = blockIdx.x * 256 + threadIdx.x;          // float4 index
    if (i < N_NODES * 16) {
        float4 v = ((float4*)h)[i];
        int f = (i & 15) * 4;
        v.x = fmaxf(v.x * sc[f + 0] + sh[f + 0], 0.f);
        v.y = fmaxf(v.y * sc[f + 1] + sh[f + 1], 0.f);
        v.z = fmaxf(v.z * sc[f + 2] + sh[f + 2], 0.f);
        v.w = fmaxf(v.w * sc[f + 3] + sh[f + 3], 0.f);
        ((float4*)h)[i] = v;
    }
}

// ---------------------------------------------------------------------------
// dense2: out = (agg/cnt) @ W2l^T + h @ W2r^T + b2.  D_OUT=40: lanes f>=40
// idle (kernel is memory-bound; acceptable). 16 nodes per block.
// ---------------------------------------------------------------------------
__global__ __launch_bounds__(256) void dense2_kernel(
    const float* __restrict__ agg, const float* __restrict__ cnt,
    const float* __restrict__ h, const float* __restrict__ W2l,
    const float* __restrict__ W2r, const float* __restrict__ b2,
    float* __restrict__ out)
{
    __shared__ float wl[64 * 40];
    __shared__ float wr[64 * 40];
    for (int idx = threadIdx.x; idx < 40 * 64; idx += 256) {
        int f = idx >> 6, k = idx & 63;        // W2[f][k], f<40
        wl[k * 40 + f] = W2l[idx];             // transposed
        wr[k * 40 + f] = W2r[idx];
    }
    __syncthreads();

    int f  = threadIdx.x & 63;
    int nl = threadIdx.x >> 6;
    int node0 = blockIdx.x * 16;
    if (f < 40) {
        float bias = b2[f];
        for (int nn = 0; nn < 4; ++nn) {
            int node = node0 + nn * 4 + nl;
            if (node < N_NODES) {
                const float* ar = agg + (size_t)node * 64;
                const float* hr = h   + (size_t)node * 64;
                float ic = 1.0f / fmaxf(cnt[node], 1.0f);
                float acca = 0.f, acch = 0.f;
#pragma unroll
                for (int k = 0; k < 64; ++k) {
                    acca += ar[k] * wl[k * 40 + f];
                    acch += hr[k] * wr[k * 40 + f];
                }
                out[(size_t)node * 40 + f] = bias + acca * ic + acch;
            }
        }
    }
}

extern "C" void kernel_launch(void* const* d_in, const int* in_sizes, int n_in,
                              void* d_out, int out_size, void* d_ws, size_t ws_size,
                              hipStream_t stream)
{
    const float* x     = (const float*)d_in[0];
    const int*   ei    = (const int*)d_in[1];   // int32 per harness convention
    const float* W1l   = (const float*)d_in[2];
    const float* W1r   = (const float*)d_in[3];
    const float* b1    = (const float*)d_in[4];
    const float* gamma = (const float*)d_in[5];
    const float* beta  = (const float*)d_in[6];
    const float* W2l   = (const float*)d_in[7];
    const float* W2r   = (const float*)d_in[8];
    const float* b2    = (const float*)d_in[9];
    float* out = (float*)d_out;

    // workspace layout (floats): agg[N*64] | hbuf[N*64] | cnt[N] | stats[256]
    float* ws    = (float*)d_ws;
    float* agg   = ws;
    float* hbuf  = agg  + (size_t)N_NODES * 64;
    float* cnt   = hbuf + (size_t)N_NODES * 64;
    float* sums  = cnt + N_NODES;      // 64
    float* sumsq = sums + 64;          // 64
    float* scale = sumsq + 64;         // 64
    float* shift = scale + 64;         // 64

    const int* src = ei;               // edge_index[0]
    const int* dst = ei + N_EDGES;     // edge_index[1]

    hipMemsetAsync(agg, 0, (size_t)N_NODES * 64 * sizeof(float), stream);
    hipMemsetAsync(cnt, 0, (size_t)(N_NODES + 128) * sizeof(float), stream);

    dim3 blk(256);
    // layer 1: scatter-mean(x) -> dense -> BN stats
    scatter_kernel<<<(N_EDGES + 3) / 4, blk, 0, stream>>>(x, src, dst, agg, cnt);
    dense1_kernel<<<(N_NODES + 63) / 64, blk, 0, stream>>>(
        agg, cnt, x, W1l, W1r, b1, hbuf, sums, sumsq);
    bn_finalize_kernel<<<1, 64, 0, stream>>>(sums, sumsq, gamma, beta, scale, shift);
    bn_apply_kernel<<<(N_NODES * 16 + 255) / 256, blk, 0, stream>>>(hbuf, scale, shift);

    // layer 2: scatter-mean(h) -> dense -> out (cnt reused: same dst list)
    hipMemsetAsync(agg, 0, (size_t)N_NODES * 64 * sizeof(float), stream);
    scatter_kernel<<<(N_EDGES + 3) / 4, blk, 0, stream>>>(hbuf, src, dst, agg, nullptr);
    dense2_kernel<<<(N_NODES + 15) / 16, blk, 0, stream>>>(
        agg, cnt, hbuf, W2l, W2r, b2, out);
}

// Round 3
// 599.637 us; speedup vs baseline: 1.8877x; 1.8877x over previous
//
#include <hip/hip_runtime.h>

#define N_NODES 100000
#define N_EDGES 1600000
#define BN_EPS 1e-5f
#define NB_SCAN 98   // ceil(100000/1024)

// broadcast lane k's value across the wave (readlane -> SGPR, free for VALU src)
// MUST only be called from wave-uniform (all-64-lanes-active) control flow:
// readlane reads inactive lanes' registers, which the compiler may not have
// materialized (this exact hazard broke R2's dense2).
__device__ __forceinline__ float bcast(float v, int k) {
    return __uint_as_float(__builtin_amdgcn_readlane(__float_as_uint(v), k));
}

// ===========================================================================
// CSR build: histogram -> 3-kernel exclusive scan -> fill
// ===========================================================================
__global__ __launch_bounds__(256) void histogram_kernel(
    const int* __restrict__ dst, int* __restrict__ deg)
{
    int e = blockIdx.x * 256 + threadIdx.x;
    if (e < N_EDGES) atomicAdd(&deg[dst[e]], 1);
}

__global__ __launch_bounds__(1024) void scan1_kernel(
    const int* __restrict__ deg, int* __restrict__ offs, int* __restrict__ bsum)
{
    __shared__ int tmp[1024];
    int gid = blockIdx.x * 1024 + threadIdx.x;
    int v = (gid < N_NODES) ? deg[gid] : 0;
    tmp[threadIdx.x] = v;
    __syncthreads();
    for (int off = 1; off < 1024; off <<= 1) {
        int t = (threadIdx.x >= off) ? tmp[threadIdx.x - off] : 0;
        __syncthreads();
        tmp[threadIdx.x] += t;
        __syncthreads();
    }
    if (gid < N_NODES) offs[gid] = tmp[threadIdx.x] - v;   // exclusive in-block
    if (threadIdx.x == 1023) bsum[blockIdx.x] = tmp[1023]; // block total
}

__global__ void scan2_kernel(int* __restrict__ bsum)
{
    __shared__ int tmp[128];
    int v = (threadIdx.x < NB_SCAN) ? bsum[threadIdx.x] : 0;
    tmp[threadIdx.x] = v;
    __syncthreads();
    for (int off = 1; off < 128; off <<= 1) {
        int t = (threadIdx.x >= off) ? tmp[threadIdx.x - off] : 0;
        __syncthreads();
        tmp[threadIdx.x] += t;
        __syncthreads();
    }
    if (threadIdx.x < NB_SCAN) bsum[threadIdx.x] = tmp[threadIdx.x] - v; // exclusive
}

__global__ __launch_bounds__(1024) void scan3_kernel(
    int* __restrict__ offs, const int* __restrict__ bsum, int* __restrict__ cursor)
{
    int gid = blockIdx.x * 1024 + threadIdx.x;
    if (gid < N_NODES) {
        int v = offs[gid] + bsum[blockIdx.x];
        offs[gid] = v;
        cursor[gid] = v;
    }
    if (gid == 0) offs[N_NODES] = N_EDGES;
}

__global__ __launch_bounds__(256) void fill_kernel(
    const int* __restrict__ src, const int* __restrict__ dst,
    int* __restrict__ cursor, int* __restrict__ nbr)
{
    int e = blockIdx.x * 256 + threadIdx.x;
    if (e < N_EDGES) {
        int p = atomicAdd(&cursor[dst[e]], 1);
        nbr[p] = src[e];
    }
}

// ===========================================================================
// gather-mean: 1 wave per node, lane = feature. 4-deep unrolled gather for
// memory-level parallelism; mean folded in.
// ===========================================================================
__global__ __launch_bounds__(256) void gather_mean_kernel(
    const float* __restrict__ feat, const int* __restrict__ offs,
    const int* __restrict__ nbr, float* __restrict__ agg)
{
    int node = blockIdx.x * 4 + (threadIdx.x >> 6);
    int lane = threadIdx.x & 63;
    if (node >= N_NODES) return;
    int beg = offs[node], end = offs[node + 1];
    float a0 = 0.f, a1 = 0.f, a2 = 0.f, a3 = 0.f;
    int j = beg;
    for (; j + 3 < end; j += 4) {
        int s0 = nbr[j], s1 = nbr[j + 1], s2 = nbr[j + 2], s3 = nbr[j + 3];
        a0 += feat[(size_t)s0 * 64 + lane];
        a1 += feat[(size_t)s1 * 64 + lane];
        a2 += feat[(size_t)s2 * 64 + lane];
        a3 += feat[(size_t)s3 * 64 + lane];
    }
    for (; j < end; ++j) a0 += feat[(size_t)nbr[j] * 64 + lane];
    float inv = 1.0f / (float)max(end - beg, 1);
    agg[(size_t)node * 64 + lane] = (a0 + a1 + a2 + a3) * inv;
}

// ===========================================================================
// dense1: h = agg @ W1l^T + x @ W1r^T + b1, + BN partial sums.
// Weight columns in VGPRs (128 regs), activation row broadcast via readlane.
// 1 wave = 1 node at a time, lane = output feature. All control flow around
// bcast() is wave-uniform. No LDS in the hot loop.
// ===========================================================================
__global__ __launch_bounds__(256) void dense1_kernel(
    const float* __restrict__ agg, const float* __restrict__ x,
    const float* __restrict__ W1l, const float* __restrict__ W1r,
    const float* __restrict__ b1, float* __restrict__ h,
    float* __restrict__ sums, float* __restrict__ sumsq)
{
    int f  = threadIdx.x & 63;
    int wv = threadIdx.x >> 6;
    float wl[64], wr[64];
#pragma unroll
    for (int k = 0; k < 64; ++k) {
        wl[k] = W1l[f * 64 + k];   // W1l[f][k]
        wr[k] = W1r[f * 64 + k];
    }
    float bias = b1[f];
    float s1 = 0.f, s2 = 0.f;
    int node0 = blockIdx.x * 64;

    for (int nn = 0; nn < 16; ++nn) {
        int node = node0 + nn * 4 + wv;          // wave-uniform
        if (node < N_NODES) {                    // wave-uniform branch
            float av = agg[(size_t)node * 64 + f];
            float xv = x[(size_t)node * 64 + f];
            float acc = bias;
#pragma unroll
            for (int k = 0; k < 64; ++k) {
                acc += bcast(av, k) * wl[k];
                acc += bcast(xv, k) * wr[k];
            }
            h[(size_t)node * 64 + f] = acc;
            s1 += acc;
            s2 += acc * acc;
        }
    }

    __shared__ float red[256];
    red[threadIdx.x] = s1;
    __syncthreads();
    if (threadIdx.x < 64) {
        float t = red[threadIdx.x] + red[threadIdx.x + 64] +
                  red[threadIdx.x + 128] + red[threadIdx.x + 192];
        atomicAdd(&sums[threadIdx.x], t);
    }
    __syncthreads();
    red[threadIdx.x] = s2;
    __syncthreads();
    if (threadIdx.x < 64) {
        float t = red[threadIdx.x] + red[threadIdx.x + 64] +
                  red[threadIdx.x + 128] + red[threadIdx.x + 192];
        atomicAdd(&sumsq[threadIdx.x], t);
    }
}

// ===========================================================================
// BN finalize + apply
// ===========================================================================
__global__ void bn_finalize_kernel(
    const float* __restrict__ sums, const float* __restrict__ sumsq,
    const float* __restrict__ gamma, const float* __restrict__ beta,
    float* __restrict__ scale, float* __restrict__ shift)
{
    int f = threadIdx.x;
    if (f < 64) {
        float inv_n = 1.0f / (float)N_NODES;
        float mu  = sums[f] * inv_n;
        float var = sumsq[f] * inv_n - mu * mu;
        float rs  = rsqrtf(var + BN_EPS);
        float sc  = gamma[f] * rs;
        scale[f] = sc;
        shift[f] = beta[f] - mu * sc;
    }
}

__global__ __launch_bounds__(256) void bn_apply_kernel(
    float* __restrict__ h, const float* __restrict__ scale,
    const float* __restrict__ shift)
{
    __shared__ float sc[64], sh[64];
    if (threadIdx.x < 64) {
        sc[threadIdx.x] = scale[threadIdx.x];
        sh[threadIdx.x] = shift[threadIdx.x];
    }
    __syncthreads();
    int i = blockIdx.x * 256 + threadIdx.x;
    if (i < N_NODES * 16) {
        float4 v = ((float4*)h)[i];
        int f = (i & 15) * 4;
        v.x = fmaxf(v.x * sc[f + 0] + sh[f + 0], 0.f);
        v.y = fmaxf(v.y * sc[f + 1] + sh[f + 1], 0.f);
        v.z = fmaxf(v.z * sc[f + 2] + sh[f + 2], 0.f);
        v.w = fmaxf(v.w * sc[f + 3] + sh[f + 3], 0.f);
        ((float4*)h)[i] = v;
    }
}

// ===========================================================================
// dense2: out = agg @ W2l^T + h @ W2r^T + b2.
// FIX vs R2: all 64 lanes run the full readlane FMA chain in UNIFORM control
// flow (lanes f>=40 use clamped weight row fc=39, results discarded); only
// the final store is predicated on f<40. readlane never executes with
// inactive source lanes.
// ===========================================================================
__global__ __launch_bounds__(256) void dense2_kernel(
    const float* __restrict__ agg, const float* __restrict__ h,
    const float* __restrict__ W2l, const float* __restrict__ W2r,
    const float* __restrict__ b2, float* __restrict__ out)
{
    int f  = threadIdx.x & 63;
    int wv = threadIdx.x >> 6;
    int fc = (f < 40) ? f : 39;    // clamp: uniform-safe, in-bounds loads
    float wl[64], wr[64];
#pragma unroll
    for (int k = 0; k < 64; ++k) {
        wl[k] = W2l[fc * 64 + k];
        wr[k] = W2r[fc * 64 + k];
    }
    float bias = b2[fc];
    int node0 = blockIdx.x * 64;

    for (int nn = 0; nn < 16; ++nn) {
        int node = node0 + nn * 4 + wv;          // wave-uniform
        if (node < N_NODES) {                    // wave-uniform branch
            float av = agg[(size_t)node * 64 + f];
            float hv = h[(size_t)node * 64 + f];
            float acc = bias;
#pragma unroll
            for (int k = 0; k < 64; ++k) {
                acc += bcast(av, k) * wl[k];
                acc += bcast(hv, k) * wr[k];
            }
            if (f < 40) out[(size_t)node * 40 + f] = acc;  // only store diverges
        }
    }
}

// ===========================================================================
// Fallback path pieces (if ws_size too small for CSR): R1-style atomic scatter.
// ===========================================================================
__global__ __launch_bounds__(256) void scatter_kernel(
    const float* __restrict__ feat, const int* __restrict__ src,
    const int* __restrict__ dst, float* __restrict__ agg,
    float* __restrict__ cnt)
{
    int e = blockIdx.x * 4 + (threadIdx.x >> 6);
    int lane = threadIdx.x & 63;
    if (e >= N_EDGES) return;
    int s = src[e];
    int d = dst[e];
    atomicAdd(&agg[(size_t)d * 64 + lane], feat[(size_t)s * 64 + lane]);
    if (cnt != nullptr && lane == 0) atomicAdd(&cnt[d], 1.0f);
}

__global__ __launch_bounds__(256) void divide_rows_kernel(
    float* __restrict__ agg, const float* __restrict__ cnt)
{
    int i = blockIdx.x * 256 + threadIdx.x;
    if (i < N_NODES * 64) {
        int n = i >> 6;
        agg[i] *= 1.0f / fmaxf(cnt[n], 1.0f);
    }
}

extern "C" void kernel_launch(void* const* d_in, const int* in_sizes, int n_in,
                              void* d_out, int out_size, void* d_ws, size_t ws_size,
                              hipStream_t stream)
{
    const float* x     = (const float*)d_in[0];
    const int*   ei    = (const int*)d_in[1];
    const float* W1l   = (const float*)d_in[2];
    const float* W1r   = (const float*)d_in[3];
    const float* b1    = (const float*)d_in[4];
    const float* gamma = (const float*)d_in[5];
    const float* beta  = (const float*)d_in[6];
    const float* W2l   = (const float*)d_in[7];
    const float* W2r   = (const float*)d_in[8];
    const float* b2    = (const float*)d_in[9];
    float* out = (float*)d_out;

    const int* src = ei;
    const int* dst = ei + N_EDGES;

    // workspace layout
    float* ws    = (float*)d_ws;
    float* agg   = ws;                               // N*64
    float* hbuf  = agg + (size_t)N_NODES * 64;       // N*64
    float* sums  = hbuf + (size_t)N_NODES * 64;      // 64
    float* sumsq = sums + 64;                        // 64
    float* scale = sumsq + 64;                       // 64
    float* shift = scale + 64;                       // 64
    int* deg    = (int*)(shift + 64);                // N
    int* offs   = deg + N_NODES;                     // N+1
    int* cursor = offs + N_NODES + 1;                // N
    int* bsum   = cursor + N_NODES;                  // 128
    int* nbr    = bsum + 128;                        // E
    size_t needed = (size_t)((char*)(nbr + N_EDGES) - (char*)d_ws);

    dim3 blk(256);

    if (ws_size >= needed) {
        // ---- CSR build (reused by both layers) ----
        hipMemsetAsync(deg, 0, (size_t)N_NODES * sizeof(int), stream);
        hipMemsetAsync(sums, 0, 256 * sizeof(float), stream);
        histogram_kernel<<<(N_EDGES + 255) / 256, blk, 0, stream>>>(dst, deg);
        scan1_kernel<<<NB_SCAN, 1024, 0, stream>>>(deg, offs, bsum);
        scan2_kernel<<<1, 128, 0, stream>>>(bsum);
        scan3_kernel<<<NB_SCAN, 1024, 0, stream>>>(offs, bsum, cursor);
        fill_kernel<<<(N_EDGES + 255) / 256, blk, 0, stream>>>(src, dst, cursor, nbr);

        // ---- layer 1 ----
        gather_mean_kernel<<<N_NODES / 4, blk, 0, stream>>>(x, offs, nbr, agg);
        dense1_kernel<<<(N_NODES + 63) / 64, blk, 0, stream>>>(
            agg, x, W1l, W1r, b1, hbuf, sums, sumsq);
        bn_finalize_kernel<<<1, 64, 0, stream>>>(sums, sumsq, gamma, beta, scale, shift);
        bn_apply_kernel<<<(N_NODES * 16 + 255) / 256, blk, 0, stream>>>(hbuf, scale, shift);

        // ---- layer 2 ----
        gather_mean_kernel<<<N_NODES / 4, blk, 0, stream>>>(hbuf, offs, nbr, agg);
        dense2_kernel<<<(N_NODES + 63) / 64, blk, 0, stream>>>(
            agg, hbuf, W2l, W2r, b2, out);
    } else {
        // ---- fallback: atomic scatter path ----
        float* cnt = (float*)deg;  // reuse slot, float counts
        hipMemsetAsync(agg, 0, (size_t)N_NODES * 64 * sizeof(float), stream);
        hipMemsetAsync(cnt, 0, (size_t)N_NODES * sizeof(float), stream);
        hipMemsetAsync(sums, 0, 256 * sizeof(float), stream);

        scatter_kernel<<<(N_EDGES + 3) / 4, blk, 0, stream>>>(x, src, dst, agg, cnt);
        divide_rows_kernel<<<(N_NODES * 64 + 255) / 256, blk, 0, stream>>>(agg, cnt);
        dense1_kernel<<<(N_NODES + 63) / 64, blk, 0, stream>>>(
            agg, x, W1l, W1r, b1, hbuf, sums, sumsq);
        bn_finalize_kernel<<<1, 64, 0, stream>>>(sums, sumsq, gamma, beta, scale, shift);
        bn_apply_kernel<<<(N_NODES * 16 + 255) / 256, blk, 0, stream>>>(hbuf, scale, shift);

        hipMemsetAsync(agg, 0, (size_t)N_NODES * 64 * sizeof(float), stream);
        scatter_kernel<<<(N_EDGES + 3) / 4, blk, 0, stream>>>(hbuf, src, dst, agg, nullptr);
        divide_rows_kernel<<<(N_NODES * 64 + 255) / 256, blk, 0, stream>>>(agg, cnt);
        dense2_kernel<<<(N_NODES + 63) / 64, blk, 0, stream>>>(
            agg, hbuf, W2l, W2r, b2, out);
    }
}